// Round 3
// baseline (552.559 us; speedup 1.0000x reference)
//
#include <hip/hip_runtime.h>

#define FD 128      // feature dim (both layers)
#define BSH 7       // log2(nodes per bucket) = 128 nodes/bucket
#define BPAD 16     // bucket cursor padding (ints) -> one per 64B line

// ---------------- CSR build ----------------

__global__ void count_kernel(const int* __restrict__ dst, int* __restrict__ cnt, int E) {
    int e = blockIdx.x * blockDim.x + threadIdx.x;
    if (e < E) atomicAdd(&cnt[dst[e]], 1);
}

// Phase 1: per-block (1024 elems) sums
__global__ __launch_bounds__(256) void scan_blocksums(
        const int* __restrict__ cnt, int* __restrict__ bsum, int N) {
    int base = blockIdx.x * 1024 + threadIdx.x * 4;
    int s = 0;
    if (base + 3 < N) {
        int4 c = *(const int4*)&cnt[base];
        s = c.x + c.y + c.z + c.w;
    } else {
        for (int i = base; i < N; ++i) s += cnt[i];
    }
    #pragma unroll
    for (int off = 32; off > 0; off >>= 1) s += __shfl_down(s, off);
    __shared__ int wsum[4];
    if ((threadIdx.x & 63) == 0) wsum[threadIdx.x >> 6] = s;
    __syncthreads();
    if (threadIdx.x == 0) bsum[blockIdx.x] = wsum[0] + wsum[1] + wsum[2] + wsum[3];
}

// Phase 2: exclusive scan of block sums (nb <= 256)
__global__ __launch_bounds__(256) void scan_offsets(
        const int* __restrict__ bsum, int* __restrict__ boff, int nb) {
    __shared__ int sm[256];
    int t = threadIdx.x;
    int v = (t < nb) ? bsum[t] : 0;
    sm[t] = v;
    __syncthreads();
    for (int off = 1; off < 256; off <<= 1) {
        int add = (t >= off) ? sm[t - off] : 0;
        __syncthreads();
        sm[t] += add;
        __syncthreads();
    }
    if (t < nb) boff[t] = sm[t] - v;
}

// Phase 3: recompute local scan, write rp/cur/dis
__global__ __launch_bounds__(256) void scan_write(
        const int* __restrict__ cnt, const int* __restrict__ boff,
        int* __restrict__ rp, int* __restrict__ cur, float* __restrict__ dis,
        int N, int E) {
    __shared__ int sm[256];
    int t = threadIdx.x;
    int base = blockIdx.x * 1024 + t * 4;
    int c[4] = {0, 0, 0, 0};
    bool full = (base + 3 < N);
    if (full) {
        int4 q = *(const int4*)&cnt[base];
        c[0] = q.x; c[1] = q.y; c[2] = q.z; c[3] = q.w;
    } else {
        for (int j = 0; j < 4; ++j) if (base + j < N) c[j] = cnt[base + j];
    }
    int s = c[0] + c[1] + c[2] + c[3];
    sm[t] = s;
    __syncthreads();
    for (int off = 1; off < 256; off <<= 1) {
        int add = (t >= off) ? sm[t - off] : 0;
        __syncthreads();
        sm[t] += add;
        __syncthreads();
    }
    int run = boff[blockIdx.x] + sm[t] - s;
    int r[4]; float d[4];
    #pragma unroll
    for (int j = 0; j < 4; ++j) {
        r[j] = run;
        d[j] = 1.0f / sqrtf((float)(c[j] + 1));  // deg includes self-loop
        run += c[j];
    }
    if (full) {
        *(int4*)&rp[base]  = make_int4(r[0], r[1], r[2], r[3]);
        *(int4*)&cur[base] = make_int4(r[0], r[1], r[2], r[3]);
        *(float4*)&dis[base] = make_float4(d[0], d[1], d[2], d[3]);
    } else {
        for (int j = 0; j < 4; ++j) if (base + j < N) {
            rp[base + j] = r[j]; cur[base + j] = r[j]; dis[base + j] = d[j];
        }
    }
    if (blockIdx.x == 0 && t == 0) rp[N] = E;
}

// Bucket cursors = rp at bucket boundaries (free from the scan)
__global__ void bucket_init(const int* __restrict__ rp, int* __restrict__ bcur,
                            int K, int N) {
    int b = blockIdx.x * blockDim.x + threadIdx.x;
    if (b < K) bcur[b * BPAD] = rp[min(b << BSH, N)];
}

// Pass B: partition edges into per-bucket regions (cursor-ordered appends ->
// lines fill sequentially while L2-hot -> ~1x write amplification)
__global__ void partition_kernel(const int* __restrict__ src, const int* __restrict__ dst,
                                 int* __restrict__ bcur, int2* __restrict__ pairs, int E) {
    int e = blockIdx.x * blockDim.x + threadIdx.x;
    if (e < E) {
        int d = dst[e];
        int s = src[e];
        int b = d >> BSH;
        int p = atomicAdd(&bcur[b * BPAD], 1);
        pairs[p] = make_int2(d, s);
    }
}

// Pass C: per-bucket scatter; col window ~16KB -> L2-resident, dense writeback
__global__ __launch_bounds__(256) void scatter_kernel(
        const int2* __restrict__ pairs, const int* __restrict__ rp,
        int* __restrict__ cur, int* __restrict__ col, int N) {
    int b = blockIdx.x;
    int beg = rp[min(b << BSH, N)];
    int end = rp[min((b + 1) << BSH, N)];
    for (int e = beg + threadIdx.x; e < end; e += 256) {
        int2 ds = pairs[e];
        int p = atomicAdd(&cur[ds.x], 1);
        col[p] = ds.y;
    }
}

// ---------------- fp32 GEMM: C[M x 128] = dis[row] * (A[M x 128] @ W[128 x 128]) ----

#define BM 64
#define BK 32

__global__ __launch_bounds__(256) void gemm_kernel(
        const float* __restrict__ A, const float* __restrict__ W,
        const float* __restrict__ dis, float* __restrict__ C, int M) {
    __shared__ float xs[BK][BM + 1];
    __shared__ float ws[BK][FD];
    int tid = threadIdx.x;
    int tx = tid & 31;
    int ty = tid >> 5;
    int rowBase = blockIdx.x * BM;
    float acc[8][4] = {};

    for (int kk = 0; kk < FD; kk += BK) {
        #pragma unroll
        for (int i = 0; i < 2; ++i) {
            int f = tid + i * 256;
            int r = f >> 3;
            int kq = (f & 7) * 4;
            int grow = rowBase + r;
            float4 v = make_float4(0.f, 0.f, 0.f, 0.f);
            if (grow < M) v = *(const float4*)&A[(size_t)grow * FD + kk + kq];
            xs[kq + 0][r] = v.x; xs[kq + 1][r] = v.y;
            xs[kq + 2][r] = v.z; xs[kq + 3][r] = v.w;
        }
        #pragma unroll
        for (int i = 0; i < 4; ++i) {
            int f = tid + i * 256;
            int k = f >> 5;
            int c = (f & 31) * 4;
            *(float4*)&ws[k][c] = *(const float4*)&W[(size_t)(kk + k) * FD + c];
        }
        __syncthreads();
        #pragma unroll
        for (int k = 0; k < BK; ++k) {
            float4 a0 = *(float4*)&xs[k][ty * 8];
            float4 a1 = *(float4*)&xs[k][ty * 8 + 4];
            float4 b  = *(float4*)&ws[k][tx * 4];
            float ar[8] = {a0.x, a0.y, a0.z, a0.w, a1.x, a1.y, a1.z, a1.w};
            #pragma unroll
            for (int r = 0; r < 8; ++r) {
                acc[r][0] = fmaf(ar[r], b.x, acc[r][0]);
                acc[r][1] = fmaf(ar[r], b.y, acc[r][1]);
                acc[r][2] = fmaf(ar[r], b.z, acc[r][2]);
                acc[r][3] = fmaf(ar[r], b.w, acc[r][3]);
            }
        }
        __syncthreads();
    }
    int rowTop = rowBase + ty * 8;
    #pragma unroll
    for (int r = 0; r < 8; ++r) {
        int grow = rowTop + r;
        if (grow < M) {
            float dv = dis[grow];
            float4 o = make_float4(dv * acc[r][0], dv * acc[r][1],
                                   dv * acc[r][2], dv * acc[r][3]);
            *(float4*)&C[(size_t)grow * FD + tx * 4] = o;
        }
    }
}

// ---------------- CSR aggregation + bias + ReLU ----------------
// h' rows are pre-scaled by dis in the GEMM epilogue.
// out[v] = relu( dis[v] * ( h'[v] + sum_u h'[u] ) + b )

__global__ __launch_bounds__(256) void agg_kernel(
        const float2* __restrict__ h, const float* __restrict__ dis,
        const int* __restrict__ rp, const int* __restrict__ col,
        const float2* __restrict__ bias, float2* __restrict__ out, int N) {
    int v = blockIdx.x * 4 + threadIdx.y;          // blockDim = (64, 4): wave per node
    v = __builtin_amdgcn_readfirstlane(v);         // wave-uniform -> scalar rp/col loads
    if (v >= N) return;
    int t = threadIdx.x;
    float dv = dis[v];
    size_t vb = (size_t)v * 64 + t;
    float2 acc = h[vb];                            // self term h'[v]
    int e = rp[v];
    int end = rp[v + 1];
    for (; e + 8 <= end; e += 8) {
        int u0 = col[e],     u1 = col[e + 1], u2 = col[e + 2], u3 = col[e + 3];
        int u4 = col[e + 4], u5 = col[e + 5], u6 = col[e + 6], u7 = col[e + 7];
        float2 h0 = h[(size_t)u0 * 64 + t];
        float2 h1 = h[(size_t)u1 * 64 + t];
        float2 h2 = h[(size_t)u2 * 64 + t];
        float2 h3 = h[(size_t)u3 * 64 + t];
        float2 h4 = h[(size_t)u4 * 64 + t];
        float2 h5 = h[(size_t)u5 * 64 + t];
        float2 h6 = h[(size_t)u6 * 64 + t];
        float2 h7 = h[(size_t)u7 * 64 + t];
        acc.x += h0.x; acc.y += h0.y;
        acc.x += h1.x; acc.y += h1.y;
        acc.x += h2.x; acc.y += h2.y;
        acc.x += h3.x; acc.y += h3.y;
        acc.x += h4.x; acc.y += h4.y;
        acc.x += h5.x; acc.y += h5.y;
        acc.x += h6.x; acc.y += h6.y;
        acc.x += h7.x; acc.y += h7.y;
    }
    for (; e < end; ++e) {
        int u = col[e];
        float2 hu = h[(size_t)u * 64 + t];
        acc.x += hu.x; acc.y += hu.y;
    }
    float2 bb = bias[t];
    float2 r;
    r.x = fmaxf(fmaf(dv, acc.x, bb.x), 0.0f);
    r.y = fmaxf(fmaf(dv, acc.y, bb.y), 0.0f);
    out[vb] = r;
}

// ---------------- launch ----------------

extern "C" void kernel_launch(void* const* d_in, const int* in_sizes, int n_in,
                              void* d_out, int out_size, void* d_ws, size_t ws_size,
                              hipStream_t stream) {
    const float* x  = (const float*)d_in[0];
    const int*   ei = (const int*)d_in[1];   // [2, E] int32
    const float* W1 = (const float*)d_in[2];
    const float* b1 = (const float*)d_in[3];
    const float* W2 = (const float*)d_in[4];
    const float* b2 = (const float*)d_in[5];

    int N = in_sizes[0] / FD;
    int E = in_sizes[1] / 2;
    const int* src = ei;
    const int* dst = ei + E;
    int K = (N + (1 << BSH) - 1) >> BSH;     // number of buckets

    char* base = (char*)d_ws;
    size_t off = 0;
    auto align256 = [](size_t v) { return (v + 255) & ~(size_t)255; };
    int*   cnt  = (int*)(base + off); off += align256((size_t)(N + 1) * 4);
    int*   rp   = (int*)(base + off); off += align256((size_t)(N + 1) * 4);
    int*   cur  = (int*)(base + off); off += align256((size_t)N * 4);
    float* dis  = (float*)(base + off); off += align256((size_t)N * 4);
    int*   bsum = (int*)(base + off); off += align256(256 * 4);
    int*   boff = (int*)(base + off); off += align256(256 * 4);
    int*   bcur = (int*)(base + off); off += align256((size_t)K * BPAD * 4);
    int*   col  = (int*)(base + off); off += align256((size_t)E * 4);
    float* hbuf = (float*)(base + off); off += align256((size_t)N * FD * 4);
    int2*  pairs = (int2*)hbuf;   // overlay: CSR build finishes before GEMM writes hbuf
    (void)ws_size; (void)n_in; (void)out_size;

    float* z1 = (float*)d_out;

    int tE = (E + 255) / 256;
    int nb = (N + 1023) / 1024;

    hipMemsetAsync(cnt, 0, (size_t)N * 4, stream);
    count_kernel    <<<tE, 256, 0, stream>>>(dst, cnt, E);
    scan_blocksums  <<<nb, 256, 0, stream>>>(cnt, bsum, N);
    scan_offsets    <<<1, 256, 0, stream>>>(bsum, boff, nb);
    scan_write      <<<nb, 256, 0, stream>>>(cnt, boff, rp, cur, dis, N, E);
    bucket_init     <<<(K + 255) / 256, 256, 0, stream>>>(rp, bcur, K, N);
    partition_kernel<<<tE, 256, 0, stream>>>(src, dst, bcur, pairs, E);
    scatter_kernel  <<<K, 256, 0, stream>>>(pairs, rp, cur, col, N);

    dim3 aggBlk(64, 4);
    int aggGrid = (N + 3) / 4;
    int gemmGrid = (N + BM - 1) / BM;

    gemm_kernel<<<gemmGrid, 256, 0, stream>>>(x, W1, dis, hbuf, N);
    agg_kernel <<<aggGrid, aggBlk, 0, stream>>>((const float2*)hbuf, dis, rp, col,
                                                (const float2*)b1, (float2*)z1, N);
    gemm_kernel<<<gemmGrid, 256, 0, stream>>>(z1, W2, dis, hbuf, N);
    agg_kernel <<<aggGrid, aggBlk, 0, stream>>>((const float2*)hbuf, dis, rp, col,
                                                (const float2*)b2, (float2*)d_out, N);
}

// Round 4
// 375.119 us; speedup vs baseline: 1.4730x; 1.4730x over previous
//
#include <hip/hip_runtime.h>

#define FD 128      // feature dim (both layers)
#define BSH 7       // log2(nodes per bucket) = 128 nodes/bucket
#define BPAD 16     // bucket cursor padding (ints) -> one per 64B line
// packed pair: (local_dst << 17) | src   -- requires N <= 131072

// ---------------- CSR build ----------------

// 391-bin histogram of dst buckets, LDS-privatized
__global__ __launch_bounds__(256) void hist_kernel(
        const int* __restrict__ dst, int* __restrict__ bhist, int E, int K) {
    __shared__ int lh[512];
    for (int i = threadIdx.x; i < K; i += 256) lh[i] = 0;
    __syncthreads();
    for (int e = blockIdx.x * 256 + threadIdx.x; e < E; e += gridDim.x * 256)
        atomicAdd(&lh[dst[e] >> BSH], 1);
    __syncthreads();
    for (int i = threadIdx.x; i < K; i += 256)
        if (lh[i]) atomicAdd(&bhist[i], lh[i]);
}

// exclusive scan of K (<=512) bucket counts; init padded cursors
__global__ __launch_bounds__(512) void bscan_kernel(
        const int* __restrict__ bhist, int* __restrict__ bbase, int* __restrict__ bcur,
        int* __restrict__ rp, int K, int E, int N) {
    __shared__ int sm[512];
    int t = threadIdx.x;
    int v = (t < K) ? bhist[t] : 0;
    sm[t] = v;
    __syncthreads();
    for (int off = 1; off < 512; off <<= 1) {
        int add = (t >= off) ? sm[t - off] : 0;
        __syncthreads();
        sm[t] += add;
        __syncthreads();
    }
    if (t < K) {
        bbase[t] = sm[t] - v;
        bcur[t * BPAD] = sm[t] - v;
    }
    if (t == 0) { bbase[K] = E; rp[N] = E; }
}

// partition edges into bucket regions (cursor-ordered appends -> dense writeback)
__global__ void partition_kernel(const int* __restrict__ src, const int* __restrict__ dst,
                                 int* __restrict__ bcur, int* __restrict__ pairs, int E) {
    int e = blockIdx.x * blockDim.x + threadIdx.x;
    if (e < E) {
        int d = dst[e];
        int s = src[e];
        int b = d >> BSH;
        int p = atomicAdd(&bcur[b * BPAD], 1);
        pairs[p] = ((d & ((1 << BSH) - 1)) << 17) | s;
    }
}

// per-bucket: count + scan + scatter in LDS; writes rp/dis/col
__global__ __launch_bounds__(256) void build_kernel(
        const int* __restrict__ pairs, const int* __restrict__ bbase,
        int* __restrict__ rp, float* __restrict__ dis, int* __restrict__ col, int N) {
    __shared__ int lcnt[1 << BSH];
    __shared__ int lsum[1 << BSH];
    __shared__ int lbase[1 << BSH];
    int b = blockIdx.x;
    int t = threadIdx.x;
    int nbase = b << BSH;
    int nn = min(1 << BSH, N - nbase);
    int beg = bbase[b], end = bbase[b + 1];
    if (t < 128) lcnt[t] = 0;
    __syncthreads();
    for (int e = beg + t; e < end; e += 256)
        atomicAdd(&lcnt[pairs[e] >> 17], 1);
    __syncthreads();
    if (t < 128) lsum[t] = lcnt[t];
    __syncthreads();
    for (int off = 1; off < 128; off <<= 1) {
        int add = (t < 128 && t >= off) ? lsum[t - off] : 0;
        __syncthreads();
        if (t < 128) lsum[t] += add;
        __syncthreads();
    }
    if (t < 128) {
        int excl = beg + lsum[t] - lcnt[t];
        lbase[t] = excl;
        if (t < nn) {
            rp[nbase + t] = excl;
            dis[nbase + t] = rsqrtf((float)(lcnt[t] + 1));  // deg incl. self-loop
        }
    }
    __syncthreads();
    if (t < 128) lcnt[t] = lbase[t];   // reuse as cursor
    __syncthreads();
    for (int e = beg + t; e < end; e += 256) {
        int p = pairs[e];
        int pos = atomicAdd(&lcnt[p >> 17], 1);
        col[pos] = p & 0x1FFFF;
    }
}

// ---------------- fp32 GEMM, bf16 output: C = bf16( dis[row] * (A @ W) ) ----------

#define BM 64
#define BK 32

__device__ inline unsigned bfr(float f) {   // fp32 -> bf16 bits, round-nearest-even
    unsigned u = __float_as_uint(f);
    return (u + 0x7FFF + ((u >> 16) & 1)) >> 16;
}

__global__ __launch_bounds__(256) void gemm_kernel(
        const float* __restrict__ A, const float* __restrict__ W,
        const float* __restrict__ dis, unsigned* __restrict__ C, int M) {
    __shared__ float xs[BK][BM + 1];
    __shared__ float ws[BK][FD];
    int tid = threadIdx.x;
    int tx = tid & 31;
    int ty = tid >> 5;
    int rowBase = blockIdx.x * BM;
    float acc[8][4] = {};

    for (int kk = 0; kk < FD; kk += BK) {
        #pragma unroll
        for (int i = 0; i < 2; ++i) {
            int f = tid + i * 256;
            int r = f >> 3;
            int kq = (f & 7) * 4;
            int grow = rowBase + r;
            float4 v = make_float4(0.f, 0.f, 0.f, 0.f);
            if (grow < M) v = *(const float4*)&A[(size_t)grow * FD + kk + kq];
            xs[kq + 0][r] = v.x; xs[kq + 1][r] = v.y;
            xs[kq + 2][r] = v.z; xs[kq + 3][r] = v.w;
        }
        #pragma unroll
        for (int i = 0; i < 4; ++i) {
            int f = tid + i * 256;
            int k = f >> 5;
            int c = (f & 31) * 4;
            *(float4*)&ws[k][c] = *(const float4*)&W[(size_t)(kk + k) * FD + c];
        }
        __syncthreads();
        #pragma unroll
        for (int k = 0; k < BK; ++k) {
            float4 a0 = *(float4*)&xs[k][ty * 8];
            float4 a1 = *(float4*)&xs[k][ty * 8 + 4];
            float4 b  = *(float4*)&ws[k][tx * 4];
            float ar[8] = {a0.x, a0.y, a0.z, a0.w, a1.x, a1.y, a1.z, a1.w};
            #pragma unroll
            for (int r = 0; r < 8; ++r) {
                acc[r][0] = fmaf(ar[r], b.x, acc[r][0]);
                acc[r][1] = fmaf(ar[r], b.y, acc[r][1]);
                acc[r][2] = fmaf(ar[r], b.z, acc[r][2]);
                acc[r][3] = fmaf(ar[r], b.w, acc[r][3]);
            }
        }
        __syncthreads();
    }
    int rowTop = rowBase + ty * 8;
    #pragma unroll
    for (int r = 0; r < 8; ++r) {
        int grow = rowTop + r;
        if (grow < M) {
            float dv = dis[grow];
            unsigned p0 = bfr(dv * acc[r][0]) | (bfr(dv * acc[r][1]) << 16);
            unsigned p1 = bfr(dv * acc[r][2]) | (bfr(dv * acc[r][3]) << 16);
            uint2 o = make_uint2(p0, p1);
            *(uint2*)&C[(size_t)grow * 64 + tx * 2] = o;   // row = 64 uints (128 bf16)
        }
    }
}

// ---------------- CSR aggregation + bias + ReLU ----------------
// h' rows pre-scaled by dis, stored bf16 (2 per uint).
// out[v] = relu( dis[v] * ( h'[v] + sum_u h'[u] ) + b ),  out fp32.

__device__ inline float uplo(unsigned p) { return __uint_as_float(p << 16); }
__device__ inline float uphi(unsigned p) { return __uint_as_float(p & 0xFFFF0000u); }

__global__ __launch_bounds__(256) void agg_kernel(
        const unsigned* __restrict__ h, const float* __restrict__ dis,
        const int* __restrict__ rp, const int* __restrict__ col,
        const float2* __restrict__ bias, float2* __restrict__ out, int N) {
    int v = blockIdx.x * 4 + threadIdx.y;          // blockDim = (64, 4): wave per node
    v = __builtin_amdgcn_readfirstlane(v);         // wave-uniform -> scalar rp/col loads
    if (v >= N) return;
    int t = threadIdx.x;
    float dv = dis[v];
    size_t vb = (size_t)v * 64 + t;
    unsigned hp = h[vb];                           // self term h'[v]
    float2 acc;
    acc.x = uplo(hp); acc.y = uphi(hp);
    int e = rp[v];
    int end = rp[v + 1];
    for (; e + 8 <= end; e += 8) {
        int u0 = col[e],     u1 = col[e + 1], u2 = col[e + 2], u3 = col[e + 3];
        int u4 = col[e + 4], u5 = col[e + 5], u6 = col[e + 6], u7 = col[e + 7];
        unsigned p0 = h[(size_t)u0 * 64 + t];
        unsigned p1 = h[(size_t)u1 * 64 + t];
        unsigned p2 = h[(size_t)u2 * 64 + t];
        unsigned p3 = h[(size_t)u3 * 64 + t];
        unsigned p4 = h[(size_t)u4 * 64 + t];
        unsigned p5 = h[(size_t)u5 * 64 + t];
        unsigned p6 = h[(size_t)u6 * 64 + t];
        unsigned p7 = h[(size_t)u7 * 64 + t];
        acc.x += uplo(p0); acc.y += uphi(p0);
        acc.x += uplo(p1); acc.y += uphi(p1);
        acc.x += uplo(p2); acc.y += uphi(p2);
        acc.x += uplo(p3); acc.y += uphi(p3);
        acc.x += uplo(p4); acc.y += uphi(p4);
        acc.x += uplo(p5); acc.y += uphi(p5);
        acc.x += uplo(p6); acc.y += uphi(p6);
        acc.x += uplo(p7); acc.y += uphi(p7);
    }
    for (; e < end; ++e) {
        unsigned p = h[(size_t)col[e] * 64 + t];
        acc.x += uplo(p); acc.y += uphi(p);
    }
    float2 bb = bias[t];
    float2 r;
    r.x = fmaxf(fmaf(dv, acc.x, bb.x), 0.0f);
    r.y = fmaxf(fmaf(dv, acc.y, bb.y), 0.0f);
    out[vb] = r;
}

// ---------------- launch ----------------

extern "C" void kernel_launch(void* const* d_in, const int* in_sizes, int n_in,
                              void* d_out, int out_size, void* d_ws, size_t ws_size,
                              hipStream_t stream) {
    const float* x  = (const float*)d_in[0];
    const int*   ei = (const int*)d_in[1];   // [2, E] int32
    const float* W1 = (const float*)d_in[2];
    const float* b1 = (const float*)d_in[3];
    const float* W2 = (const float*)d_in[4];
    const float* b2 = (const float*)d_in[5];

    int N = in_sizes[0] / FD;
    int E = in_sizes[1] / 2;
    const int* src = ei;
    const int* dst = ei + E;
    int K = (N + (1 << BSH) - 1) >> BSH;     // number of buckets (<= 512 assumed)

    char* base = (char*)d_ws;
    size_t off = 0;
    auto align256 = [](size_t v) { return (v + 255) & ~(size_t)255; };
    int*      rp    = (int*)(base + off); off += align256((size_t)(N + 1) * 4);
    float*    dis   = (float*)(base + off); off += align256((size_t)N * 4);
    int*      bhist = (int*)(base + off); off += align256(512 * 4);
    int*      bbase = (int*)(base + off); off += align256(513 * 4);
    int*      bcur  = (int*)(base + off); off += align256((size_t)K * BPAD * 4);
    int*      pairs = (int*)(base + off); off += align256((size_t)E * 4);
    int*      col   = (int*)(base + off); off += align256((size_t)E * 4);
    unsigned* hbuf  = (unsigned*)(base + off); off += align256((size_t)N * 64 * 4);
    (void)ws_size; (void)n_in; (void)out_size;

    float* z1 = (float*)d_out;

    int tE = (E + 255) / 256;

    hipMemsetAsync(bhist, 0, 512 * 4, stream);
    hist_kernel     <<<1024, 256, 0, stream>>>(dst, bhist, E, K);
    bscan_kernel    <<<1, 512, 0, stream>>>(bhist, bbase, bcur, rp, K, E, N);
    partition_kernel<<<tE, 256, 0, stream>>>(src, dst, bcur, pairs, E);
    build_kernel    <<<K, 256, 0, stream>>>(pairs, bbase, rp, dis, col, N);

    dim3 aggBlk(64, 4);
    int aggGrid = (N + 3) / 4;
    int gemmGrid = (N + BM - 1) / BM;

    gemm_kernel<<<gemmGrid, 256, 0, stream>>>(x, W1, dis, hbuf, N);
    agg_kernel <<<aggGrid, aggBlk, 0, stream>>>(hbuf, dis, rp, col,
                                                (const float2*)b1, (float2*)z1, N);
    gemm_kernel<<<gemmGrid, 256, 0, stream>>>(z1, W2, dis, hbuf, N);
    agg_kernel <<<aggGrid, aggBlk, 0, stream>>>(hbuf, dis, rp, col,
                                                (const float2*)b2, (float2*)d_out, N);
}

// Round 5
// 371.629 us; speedup vs baseline: 1.4869x; 1.0094x over previous
//
#include <hip/hip_runtime.h>

#define FD 128      // feature dim (both layers)
#define BSH 7       // log2(nodes per bucket) = 128 nodes/bucket
#define G 8         // sub-regions per bucket (one per XCD under round-robin dispatch)
#define BPAD 16     // cursor padding (ints) -> one per 64B line
// packed pair: (local_dst << 17) | src   -- requires N <= 131072

// ---------------- CSR build ----------------

// Per-(bucket, group) histogram. g = blockIdx&7 == (e>>8)&7 for every edge this
// block touches (grid 1024 = multiple of 8), matching partition_kernel exactly.
__global__ __launch_bounds__(256) void hist_kernel(
        const int* __restrict__ dst, int* __restrict__ bhist, int E, int K) {
    __shared__ int lh[512];
    int g = blockIdx.x & (G - 1);
    for (int i = threadIdx.x; i < K; i += 256) lh[i] = 0;
    __syncthreads();
    for (int e = blockIdx.x * 256 + threadIdx.x; e < E; e += gridDim.x * 256)
        atomicAdd(&lh[dst[e] >> BSH], 1);
    __syncthreads();
    for (int i = threadIdx.x; i < K; i += 256)
        if (lh[i]) atomicAdd(&bhist[i * G + g], lh[i]);
}

// Exclusive scan of KG (= K*8, <= 4096) bin counts; init padded cursors.
__global__ __launch_bounds__(1024) void bscan_kernel(
        const int* __restrict__ bhist, int* __restrict__ bbase, int* __restrict__ bcur,
        int* __restrict__ rp, int KG, int E, int N) {
    __shared__ int sm[1024];
    int t = threadIdx.x;
    int v[4];
    int s = 0;
    #pragma unroll
    for (int j = 0; j < 4; ++j) {
        int i = t * 4 + j;
        v[j] = (i < KG) ? bhist[i] : 0;
        s += v[j];
    }
    sm[t] = s;
    __syncthreads();
    for (int off = 1; off < 1024; off <<= 1) {
        int add = (t >= off) ? sm[t - off] : 0;
        __syncthreads();
        sm[t] += add;
        __syncthreads();
    }
    int run = sm[t] - s;   // exclusive prefix of this thread's 4 bins
    #pragma unroll
    for (int j = 0; j < 4; ++j) {
        int i = t * 4 + j;
        if (i < KG) { bbase[i] = run; bcur[i * BPAD] = run; }
        run += v[j];
    }
    if (t == 0) { bbase[KG] = E; rp[N] = E; }
}

// Partition edges into per-(bucket, group) regions. All appends to a given
// region come from blocks with the same blockIdx&7 -> same XCD (round-robin
// dispatch) -> lines accumulate in ONE L2 -> dense writeback.
__global__ void partition_kernel(const int* __restrict__ src, const int* __restrict__ dst,
                                 int* __restrict__ bcur, int* __restrict__ pairs, int E) {
    int g = blockIdx.x & (G - 1);
    int e = blockIdx.x * blockDim.x + threadIdx.x;
    if (e < E) {
        int d = dst[e];
        int s = src[e];
        int bin = (d >> BSH) * G + g;
        int p = atomicAdd(&bcur[bin * BPAD], 1);
        pairs[p] = ((d & ((1 << BSH) - 1)) << 17) | s;
    }
}

// Per-bucket: count + scan + scatter in LDS; writes rp/dis/col.
// Bucket b's edges are contiguous: [bbase[b*G], bbase[(b+1)*G]).
__global__ __launch_bounds__(256) void build_kernel(
        const int* __restrict__ pairs, const int* __restrict__ bbase,
        int* __restrict__ rp, float* __restrict__ dis, int* __restrict__ col, int N) {
    __shared__ int lcnt[1 << BSH];
    __shared__ int lsum[1 << BSH];
    __shared__ int lbase[1 << BSH];
    int b = blockIdx.x;
    int t = threadIdx.x;
    int nbase = b << BSH;
    int nn = min(1 << BSH, N - nbase);
    int beg = bbase[b * G], end = bbase[(b + 1) * G];
    if (t < 128) lcnt[t] = 0;
    __syncthreads();
    for (int e = beg + t; e < end; e += 256)
        atomicAdd(&lcnt[pairs[e] >> 17], 1);
    __syncthreads();
    if (t < 128) lsum[t] = lcnt[t];
    __syncthreads();
    for (int off = 1; off < 128; off <<= 1) {
        int add = (t < 128 && t >= off) ? lsum[t - off] : 0;
        __syncthreads();
        if (t < 128) lsum[t] += add;
        __syncthreads();
    }
    if (t < 128) {
        int excl = beg + lsum[t] - lcnt[t];
        lbase[t] = excl;
        if (t < nn) {
            rp[nbase + t] = excl;
            dis[nbase + t] = rsqrtf((float)(lcnt[t] + 1));  // deg incl. self-loop
        }
    }
    __syncthreads();
    if (t < 128) lcnt[t] = lbase[t];   // reuse as cursor
    __syncthreads();
    for (int e = beg + t; e < end; e += 256) {
        int p = pairs[e];
        int pos = atomicAdd(&lcnt[p >> 17], 1);
        col[pos] = p & 0x1FFFF;
    }
}

// ---------------- fp32 GEMM, bf16 output: C = bf16( dis[row] * (A @ W) ) ----------

#define BM 64
#define BK 32

__device__ inline unsigned bfr(float f) {   // fp32 -> bf16 bits, round-nearest-even
    unsigned u = __float_as_uint(f);
    return (u + 0x7FFF + ((u >> 16) & 1)) >> 16;
}

__global__ __launch_bounds__(256) void gemm_kernel(
        const float* __restrict__ A, const float* __restrict__ W,
        const float* __restrict__ dis, unsigned* __restrict__ C, int M) {
    __shared__ float xs[BK][BM + 1];
    __shared__ float ws[BK][FD];
    int tid = threadIdx.x;
    int tx = tid & 31;
    int ty = tid >> 5;
    int rowBase = blockIdx.x * BM;
    float acc[8][4] = {};

    for (int kk = 0; kk < FD; kk += BK) {
        #pragma unroll
        for (int i = 0; i < 2; ++i) {
            int f = tid + i * 256;
            int r = f >> 3;
            int kq = (f & 7) * 4;
            int grow = rowBase + r;
            float4 v = make_float4(0.f, 0.f, 0.f, 0.f);
            if (grow < M) v = *(const float4*)&A[(size_t)grow * FD + kk + kq];
            xs[kq + 0][r] = v.x; xs[kq + 1][r] = v.y;
            xs[kq + 2][r] = v.z; xs[kq + 3][r] = v.w;
        }
        #pragma unroll
        for (int i = 0; i < 4; ++i) {
            int f = tid + i * 256;
            int k = f >> 5;
            int c = (f & 31) * 4;
            *(float4*)&ws[k][c] = *(const float4*)&W[(size_t)(kk + k) * FD + c];
        }
        __syncthreads();
        #pragma unroll
        for (int k = 0; k < BK; ++k) {
            float4 a0 = *(float4*)&xs[k][ty * 8];
            float4 a1 = *(float4*)&xs[k][ty * 8 + 4];
            float4 b  = *(float4*)&ws[k][tx * 4];
            float ar[8] = {a0.x, a0.y, a0.z, a0.w, a1.x, a1.y, a1.z, a1.w};
            #pragma unroll
            for (int r = 0; r < 8; ++r) {
                acc[r][0] = fmaf(ar[r], b.x, acc[r][0]);
                acc[r][1] = fmaf(ar[r], b.y, acc[r][1]);
                acc[r][2] = fmaf(ar[r], b.z, acc[r][2]);
                acc[r][3] = fmaf(ar[r], b.w, acc[r][3]);
            }
        }
        __syncthreads();
    }
    int rowTop = rowBase + ty * 8;
    #pragma unroll
    for (int r = 0; r < 8; ++r) {
        int grow = rowTop + r;
        if (grow < M) {
            float dv = dis[grow];
            unsigned p0 = bfr(dv * acc[r][0]) | (bfr(dv * acc[r][1]) << 16);
            unsigned p1 = bfr(dv * acc[r][2]) | (bfr(dv * acc[r][3]) << 16);
            uint2 o = make_uint2(p0, p1);
            *(uint2*)&C[(size_t)grow * 64 + tx * 2] = o;   // row = 64 uints (128 bf16)
        }
    }
}

// ---------------- CSR aggregation + bias + ReLU ----------------
// h' rows pre-scaled by dis, stored bf16 (2 per uint).
// out[v] = relu( dis[v] * ( h'[v] + sum_u h'[u] ) + b ),  out fp32.

__device__ inline float uplo(unsigned p) { return __uint_as_float(p << 16); }
__device__ inline float uphi(unsigned p) { return __uint_as_float(p & 0xFFFF0000u); }

__global__ __launch_bounds__(256) void agg_kernel(
        const unsigned* __restrict__ h, const float* __restrict__ dis,
        const int* __restrict__ rp, const int* __restrict__ col,
        const float2* __restrict__ bias, float2* __restrict__ out, int N) {
    int v = blockIdx.x * 4 + threadIdx.y;          // blockDim = (64, 4): wave per node
    v = __builtin_amdgcn_readfirstlane(v);         // wave-uniform -> scalar rp/col loads
    if (v >= N) return;
    int t = threadIdx.x;
    float dv = dis[v];
    size_t vb = (size_t)v * 64 + t;
    unsigned hp = h[vb];                           // self term h'[v]
    float2 acc;
    acc.x = uplo(hp); acc.y = uphi(hp);
    int e = rp[v];
    int end = rp[v + 1];
    for (; e + 8 <= end; e += 8) {
        int u0 = col[e],     u1 = col[e + 1], u2 = col[e + 2], u3 = col[e + 3];
        int u4 = col[e + 4], u5 = col[e + 5], u6 = col[e + 6], u7 = col[e + 7];
        unsigned p0 = h[(size_t)u0 * 64 + t];
        unsigned p1 = h[(size_t)u1 * 64 + t];
        unsigned p2 = h[(size_t)u2 * 64 + t];
        unsigned p3 = h[(size_t)u3 * 64 + t];
        unsigned p4 = h[(size_t)u4 * 64 + t];
        unsigned p5 = h[(size_t)u5 * 64 + t];
        unsigned p6 = h[(size_t)u6 * 64 + t];
        unsigned p7 = h[(size_t)u7 * 64 + t];
        acc.x += uplo(p0); acc.y += uphi(p0);
        acc.x += uplo(p1); acc.y += uphi(p1);
        acc.x += uplo(p2); acc.y += uphi(p2);
        acc.x += uplo(p3); acc.y += uphi(p3);
        acc.x += uplo(p4); acc.y += uphi(p4);
        acc.x += uplo(p5); acc.y += uphi(p5);
        acc.x += uplo(p6); acc.y += uphi(p6);
        acc.x += uplo(p7); acc.y += uphi(p7);
    }
    for (; e < end; ++e) {
        unsigned p = h[(size_t)col[e] * 64 + t];
        acc.x += uplo(p); acc.y += uphi(p);
    }
    float2 bb = bias[t];
    float2 r;
    r.x = fmaxf(fmaf(dv, acc.x, bb.x), 0.0f);
    r.y = fmaxf(fmaf(dv, acc.y, bb.y), 0.0f);
    out[vb] = r;
}

// ---------------- launch ----------------

extern "C" void kernel_launch(void* const* d_in, const int* in_sizes, int n_in,
                              void* d_out, int out_size, void* d_ws, size_t ws_size,
                              hipStream_t stream) {
    const float* x  = (const float*)d_in[0];
    const int*   ei = (const int*)d_in[1];   // [2, E] int32
    const float* W1 = (const float*)d_in[2];
    const float* b1 = (const float*)d_in[3];
    const float* W2 = (const float*)d_in[4];
    const float* b2 = (const float*)d_in[5];

    int N = in_sizes[0] / FD;
    int E = in_sizes[1] / 2;
    const int* src = ei;
    const int* dst = ei + E;
    int K = (N + (1 << BSH) - 1) >> BSH;     // buckets
    int KG = K * G;                           // (bucket, group) bins

    char* base = (char*)d_ws;
    size_t off = 0;
    auto align256 = [](size_t v) { return (v + 255) & ~(size_t)255; };
    int*      rp    = (int*)(base + off); off += align256((size_t)(N + 1) * 4);
    float*    dis   = (float*)(base + off); off += align256((size_t)N * 4);
    int*      bhist = (int*)(base + off); off += align256((size_t)KG * 4);
    int*      bbase = (int*)(base + off); off += align256((size_t)(KG + 1) * 4);
    int*      bcur  = (int*)(base + off); off += align256((size_t)KG * BPAD * 4);
    int*      pairs = (int*)(base + off); off += align256((size_t)E * 4);
    int*      col   = (int*)(base + off); off += align256((size_t)E * 4);
    unsigned* hbuf  = (unsigned*)(base + off); off += align256((size_t)N * 64 * 4);
    (void)ws_size; (void)n_in; (void)out_size;

    float* z1 = (float*)d_out;

    int tE = (E + 255) / 256;

    hipMemsetAsync(bhist, 0, (size_t)KG * 4, stream);
    hist_kernel     <<<1024, 256, 0, stream>>>(dst, bhist, E, K);
    bscan_kernel    <<<1, 1024, 0, stream>>>(bhist, bbase, bcur, rp, KG, E, N);
    partition_kernel<<<tE, 256, 0, stream>>>(src, dst, bcur, pairs, E);
    build_kernel    <<<K, 256, 0, stream>>>(pairs, bbase, rp, dis, col, N);

    dim3 aggBlk(64, 4);
    int aggGrid = (N + 3) / 4;
    int gemmGrid = (N + BM - 1) / BM;

    gemm_kernel<<<gemmGrid, 256, 0, stream>>>(x, W1, dis, hbuf, N);
    agg_kernel <<<aggGrid, aggBlk, 0, stream>>>(hbuf, dis, rp, col,
                                                (const float2*)b1, (float2*)z1, N);
    gemm_kernel<<<gemmGrid, 256, 0, stream>>>(z1, W2, dis, hbuf, N);
    agg_kernel <<<aggGrid, aggBlk, 0, stream>>>(hbuf, dis, rp, col,
                                                (const float2*)b2, (float2*)d_out, N);
}

// Round 6
// 306.306 us; speedup vs baseline: 1.8039x; 1.2133x over previous
//
#include <hip/hip_runtime.h>

#define FD 128      // feature dim (both layers)
#define BSH 7       // log2(nodes per bucket) = 128 nodes/bucket
#define BPAD 16     // cursor padding (ints) -> one per 64B line
#define CH 4096     // edges per partition block
#define CHT 16      // edges per thread (CH / 256)
// packed pair: (local_dst << 17) | src   -- requires N <= 131072

// ---------------- CSR build ----------------

// K-bin histogram of dst buckets, LDS-privatized
__global__ __launch_bounds__(256) void hist_kernel(
        const int* __restrict__ dst, int* __restrict__ bhist, int E, int K) {
    __shared__ int lh[512];
    for (int i = threadIdx.x; i < K; i += 256) lh[i] = 0;
    __syncthreads();
    for (int e = blockIdx.x * 256 + threadIdx.x; e < E; e += gridDim.x * 256)
        atomicAdd(&lh[dst[e] >> BSH], 1);
    __syncthreads();
    for (int i = threadIdx.x; i < K; i += 256)
        if (lh[i]) atomicAdd(&bhist[i], lh[i]);
}

// exclusive scan of K (<=512) bucket counts; init padded cursors
__global__ __launch_bounds__(512) void bscan_kernel(
        const int* __restrict__ bhist, int* __restrict__ bbase, int* __restrict__ bcur,
        int* __restrict__ rp, int K, int E, int N) {
    __shared__ int sm[512];
    int t = threadIdx.x;
    int v = (t < K) ? bhist[t] : 0;
    sm[t] = v;
    __syncthreads();
    for (int off = 1; off < 512; off <<= 1) {
        int add = (t >= off) ? sm[t - off] : 0;
        __syncthreads();
        sm[t] += add;
        __syncthreads();
    }
    if (t < K) { bbase[t] = sm[t] - v; bcur[t * BPAD] = sm[t] - v; }
    if (t == 0) { bbase[K] = E; rp[N] = E; }
}

// Block-local multi-split partition: bin a 4096-edge chunk in LDS, reserve
// per-bucket global space with ONE atomic per (block,bucket), stream runs out.
// Runs (~10 entries) land in single bursts -> ~1-2 writebacks per pairs-line
// irrespective of block->XCD placement.
__global__ __launch_bounds__(256) void partition_kernel(
        const int* __restrict__ src, const int* __restrict__ dst,
        int* __restrict__ bcur, int* __restrict__ pairs, int E) {
    __shared__ int   lcnt[512];     // counts, then reused as LDS scatter cursor
    __shared__ int   lstart[512];   // local exclusive prefix
    __shared__ int   ldelta[512];   // global_reserved - lstart
    __shared__ int   sm[256];
    __shared__ int   staged[CH];
    __shared__ short binof[CH];
    int t = threadIdx.x;
    int base = blockIdx.x * CH;
    int n = min(CH, E - base);

    lcnt[t] = 0; lcnt[t + 256] = 0;
    __syncthreads();

    int pk[CHT]; int bn[CHT];
    #pragma unroll
    for (int j = 0; j < CHT; ++j) {
        int i = t + j * 256;
        bn[j] = -1;
        if (i < n) {
            int d = dst[base + i];
            int s = src[base + i];
            bn[j] = d >> BSH;
            pk[j] = ((d & ((1 << BSH) - 1)) << 17) | s;
            atomicAdd(&lcnt[bn[j]], 1);
        }
    }
    __syncthreads();

    // exclusive scan of 512 bins, 2 consecutive bins per thread
    int c0 = lcnt[2 * t], c1 = lcnt[2 * t + 1];
    int s2 = c0 + c1;
    sm[t] = s2;
    __syncthreads();
    for (int off = 1; off < 256; off <<= 1) {
        int add = (t >= off) ? sm[t - off] : 0;
        __syncthreads();
        sm[t] += add;
        __syncthreads();
    }
    int ex = sm[t] - s2;
    lstart[2 * t] = ex;     lstart[2 * t + 1] = ex + c0;
    lcnt[2 * t]   = ex;     lcnt[2 * t + 1]   = ex + c0;   // cursor for scatter
    __syncthreads();

    // scatter chunk into staged[], sorted by bucket
    #pragma unroll
    for (int j = 0; j < CHT; ++j) {
        if (bn[j] >= 0) {
            int pos = atomicAdd(&lcnt[bn[j]], 1);
            staged[pos] = pk[j];
            binof[pos] = (short)bn[j];
        }
    }
    __syncthreads();

    // global reserve per bucket (one atomic per non-empty (block,bucket))
    #pragma unroll
    for (int k = 0; k < 2; ++k) {
        int b = 2 * t + k;
        int cnt = lcnt[b] - lstart[b];
        if (cnt > 0) {
            int g = atomicAdd(&bcur[b * BPAD], cnt);
            ldelta[b] = g - lstart[b];
        }
    }
    __syncthreads();

    // stream runs out: consecutive i in a bucket -> consecutive global slots
    for (int i = t; i < n; i += 256)
        pairs[ldelta[binof[i]] + i] = staged[i];
}

// Per-bucket: count + scan + scatter in LDS; writes rp/dis/col.
__global__ __launch_bounds__(256) void build_kernel(
        const int* __restrict__ pairs, const int* __restrict__ bbase,
        int* __restrict__ rp, float* __restrict__ dis, int* __restrict__ col, int N) {
    __shared__ int lcnt[1 << BSH];
    __shared__ int lsum[1 << BSH];
    __shared__ int lbase[1 << BSH];
    int b = blockIdx.x;
    int t = threadIdx.x;
    int nbase = b << BSH;
    int nn = min(1 << BSH, N - nbase);
    int beg = bbase[b], end = bbase[b + 1];
    if (t < 128) lcnt[t] = 0;
    __syncthreads();
    for (int e = beg + t; e < end; e += 256)
        atomicAdd(&lcnt[pairs[e] >> 17], 1);
    __syncthreads();
    if (t < 128) lsum[t] = lcnt[t];
    __syncthreads();
    for (int off = 1; off < 128; off <<= 1) {
        int add = (t < 128 && t >= off) ? lsum[t - off] : 0;
        __syncthreads();
        if (t < 128) lsum[t] += add;
        __syncthreads();
    }
    if (t < 128) {
        int excl = beg + lsum[t] - lcnt[t];
        lbase[t] = excl;
        if (t < nn) {
            rp[nbase + t] = excl;
            dis[nbase + t] = rsqrtf((float)(lcnt[t] + 1));  // deg incl. self-loop
        }
    }
    __syncthreads();
    if (t < 128) lcnt[t] = lbase[t];   // reuse as cursor
    __syncthreads();
    for (int e = beg + t; e < end; e += 256) {
        int p = pairs[e];
        int pos = atomicAdd(&lcnt[p >> 17], 1);
        col[pos] = p & 0x1FFFF;
    }
}

// ---------------- fp32 GEMM, bf16 output: C = bf16( dis[row] * (A @ W) ) ----------

#define BM 64
#define BK 32

__device__ inline unsigned bfr(float f) {   // fp32 -> bf16 bits, round-nearest-even
    unsigned u = __float_as_uint(f);
    return (u + 0x7FFF + ((u >> 16) & 1)) >> 16;
}

__global__ __launch_bounds__(256) void gemm_kernel(
        const float* __restrict__ A, const float* __restrict__ W,
        const float* __restrict__ dis, unsigned* __restrict__ C, int M) {
    __shared__ float xs[BK][BM + 1];
    __shared__ float ws[BK][FD];
    int tid = threadIdx.x;
    int tx = tid & 31;
    int ty = tid >> 5;
    int rowBase = blockIdx.x * BM;
    float acc[8][4] = {};

    for (int kk = 0; kk < FD; kk += BK) {
        #pragma unroll
        for (int i = 0; i < 2; ++i) {
            int f = tid + i * 256;
            int r = f >> 3;
            int kq = (f & 7) * 4;
            int grow = rowBase + r;
            float4 v = make_float4(0.f, 0.f, 0.f, 0.f);
            if (grow < M) v = *(const float4*)&A[(size_t)grow * FD + kk + kq];
            xs[kq + 0][r] = v.x; xs[kq + 1][r] = v.y;
            xs[kq + 2][r] = v.z; xs[kq + 3][r] = v.w;
        }
        #pragma unroll
        for (int i = 0; i < 4; ++i) {
            int f = tid + i * 256;
            int k = f >> 5;
            int c = (f & 31) * 4;
            *(float4*)&ws[k][c] = *(const float4*)&W[(size_t)(kk + k) * FD + c];
        }
        __syncthreads();
        #pragma unroll
        for (int k = 0; k < BK; ++k) {
            float4 a0 = *(float4*)&xs[k][ty * 8];
            float4 a1 = *(float4*)&xs[k][ty * 8 + 4];
            float4 b  = *(float4*)&ws[k][tx * 4];
            float ar[8] = {a0.x, a0.y, a0.z, a0.w, a1.x, a1.y, a1.z, a1.w};
            #pragma unroll
            for (int r = 0; r < 8; ++r) {
                acc[r][0] = fmaf(ar[r], b.x, acc[r][0]);
                acc[r][1] = fmaf(ar[r], b.y, acc[r][1]);
                acc[r][2] = fmaf(ar[r], b.z, acc[r][2]);
                acc[r][3] = fmaf(ar[r], b.w, acc[r][3]);
            }
        }
        __syncthreads();
    }
    int rowTop = rowBase + ty * 8;
    #pragma unroll
    for (int r = 0; r < 8; ++r) {
        int grow = rowTop + r;
        if (grow < M) {
            float dv = dis[grow];
            unsigned p0 = bfr(dv * acc[r][0]) | (bfr(dv * acc[r][1]) << 16);
            unsigned p1 = bfr(dv * acc[r][2]) | (bfr(dv * acc[r][3]) << 16);
            uint2 o = make_uint2(p0, p1);
            *(uint2*)&C[(size_t)grow * 64 + tx * 2] = o;   // row = 64 uints (128 bf16)
        }
    }
}

// ---------------- CSR aggregation + bias + ReLU ----------------
// h' rows pre-scaled by dis, stored bf16 (2 per uint).
// out[v] = relu( dis[v] * ( h'[v] + sum_u h'[u] ) + b ),  out fp32.

__device__ inline float uplo(unsigned p) { return __uint_as_float(p << 16); }
__device__ inline float uphi(unsigned p) { return __uint_as_float(p & 0xFFFF0000u); }

__global__ __launch_bounds__(256) void agg_kernel(
        const unsigned* __restrict__ h, const float* __restrict__ dis,
        const int* __restrict__ rp, const int* __restrict__ col,
        const float2* __restrict__ bias, float2* __restrict__ out, int N) {
    int v = blockIdx.x * 4 + threadIdx.y;          // blockDim = (64, 4): wave per node
    v = __builtin_amdgcn_readfirstlane(v);         // wave-uniform -> scalar rp/col loads
    if (v >= N) return;
    int t = threadIdx.x;
    float dv = dis[v];
    size_t vb = (size_t)v * 64 + t;
    unsigned hp = h[vb];                           // self term h'[v]
    float2 acc;
    acc.x = uplo(hp); acc.y = uphi(hp);
    int e = rp[v];
    int end = rp[v + 1];
    for (; e + 8 <= end; e += 8) {
        int u0 = col[e],     u1 = col[e + 1], u2 = col[e + 2], u3 = col[e + 3];
        int u4 = col[e + 4], u5 = col[e + 5], u6 = col[e + 6], u7 = col[e + 7];
        unsigned p0 = h[(size_t)u0 * 64 + t];
        unsigned p1 = h[(size_t)u1 * 64 + t];
        unsigned p2 = h[(size_t)u2 * 64 + t];
        unsigned p3 = h[(size_t)u3 * 64 + t];
        unsigned p4 = h[(size_t)u4 * 64 + t];
        unsigned p5 = h[(size_t)u5 * 64 + t];
        unsigned p6 = h[(size_t)u6 * 64 + t];
        unsigned p7 = h[(size_t)u7 * 64 + t];
        acc.x += uplo(p0); acc.y += uphi(p0);
        acc.x += uplo(p1); acc.y += uphi(p1);
        acc.x += uplo(p2); acc.y += uphi(p2);
        acc.x += uplo(p3); acc.y += uphi(p3);
        acc.x += uplo(p4); acc.y += uphi(p4);
        acc.x += uplo(p5); acc.y += uphi(p5);
        acc.x += uplo(p6); acc.y += uphi(p6);
        acc.x += uplo(p7); acc.y += uphi(p7);
    }
    for (; e < end; ++e) {
        unsigned p = h[(size_t)col[e] * 64 + t];
        acc.x += uplo(p); acc.y += uphi(p);
    }
    float2 bb = bias[t];
    float2 r;
    r.x = fmaxf(fmaf(dv, acc.x, bb.x), 0.0f);
    r.y = fmaxf(fmaf(dv, acc.y, bb.y), 0.0f);
    out[vb] = r;
}

// ---------------- launch ----------------

extern "C" void kernel_launch(void* const* d_in, const int* in_sizes, int n_in,
                              void* d_out, int out_size, void* d_ws, size_t ws_size,
                              hipStream_t stream) {
    const float* x  = (const float*)d_in[0];
    const int*   ei = (const int*)d_in[1];   // [2, E] int32
    const float* W1 = (const float*)d_in[2];
    const float* b1 = (const float*)d_in[3];
    const float* W2 = (const float*)d_in[4];
    const float* b2 = (const float*)d_in[5];

    int N = in_sizes[0] / FD;
    int E = in_sizes[1] / 2;
    const int* src = ei;
    const int* dst = ei + E;
    int K = (N + (1 << BSH) - 1) >> BSH;     // buckets (<= 512 assumed)

    char* base = (char*)d_ws;
    size_t off = 0;
    auto align256 = [](size_t v) { return (v + 255) & ~(size_t)255; };
    int*      rp    = (int*)(base + off); off += align256((size_t)(N + 1) * 4);
    float*    dis   = (float*)(base + off); off += align256((size_t)N * 4);
    int*      bhist = (int*)(base + off); off += align256(512 * 4);
    int*      bbase = (int*)(base + off); off += align256(513 * 4);
    int*      bcur  = (int*)(base + off); off += align256((size_t)K * BPAD * 4);
    int*      pairs = (int*)(base + off); off += align256((size_t)E * 4);
    int*      col   = (int*)(base + off); off += align256((size_t)E * 4);
    unsigned* hbuf  = (unsigned*)(base + off); off += align256((size_t)N * 64 * 4);
    (void)ws_size; (void)n_in; (void)out_size;

    float* z1 = (float*)d_out;

    int PB = (E + CH - 1) / CH;

    hipMemsetAsync(bhist, 0, 512 * 4, stream);
    hist_kernel     <<<1024, 256, 0, stream>>>(dst, bhist, E, K);
    bscan_kernel    <<<1, 512, 0, stream>>>(bhist, bbase, bcur, rp, K, E, N);
    partition_kernel<<<PB, 256, 0, stream>>>(src, dst, bcur, pairs, E);
    build_kernel    <<<K, 256, 0, stream>>>(pairs, bbase, rp, dis, col, N);

    dim3 aggBlk(64, 4);
    int aggGrid = (N + 3) / 4;
    int gemmGrid = (N + BM - 1) / BM;

    gemm_kernel<<<gemmGrid, 256, 0, stream>>>(x, W1, dis, hbuf, N);
    agg_kernel <<<aggGrid, aggBlk, 0, stream>>>(hbuf, dis, rp, col,
                                                (const float2*)b1, (float2*)z1, N);
    gemm_kernel<<<gemmGrid, 256, 0, stream>>>(z1, W2, dis, hbuf, N);
    agg_kernel <<<aggGrid, aggBlk, 0, stream>>>(hbuf, dis, rp, col,
                                                (const float2*)b2, (float2*)d_out, N);
}

// Round 7
// 277.666 us; speedup vs baseline: 1.9900x; 1.1031x over previous
//
#include <hip/hip_runtime.h>

#define FD 128      // feature dim (both layers)
#define BSH 7       // log2(nodes per bucket) = 128 nodes/bucket
#define BPAD 16     // cursor padding (ints) -> one per 64B line
#define CH 4096     // edges per partition block
#define CHT 16      // edges per thread (CH / 256)
// packed pair: (local_dst << 17) | src   -- requires N <= 131072

typedef __attribute__((ext_vector_type(8))) short bf16x8;
typedef __attribute__((ext_vector_type(4))) float f32x4;

__device__ inline unsigned bfr(float f) {   // fp32 -> bf16 bits, round-nearest-even
    unsigned u = __float_as_uint(f);
    return (u + 0x7FFF + ((u >> 16) & 1)) >> 16;
}
__device__ inline float uplo(unsigned p) { return __uint_as_float(p << 16); }
__device__ inline float uphi(unsigned p) { return __uint_as_float(p & 0xFFFF0000u); }

// ---------------- CSR build ----------------

__global__ __launch_bounds__(256) void hist_kernel(
        const int* __restrict__ dst, int* __restrict__ bhist, int E, int K) {
    __shared__ int lh[512];
    for (int i = threadIdx.x; i < K; i += 256) lh[i] = 0;
    __syncthreads();
    for (int e = blockIdx.x * 256 + threadIdx.x; e < E; e += gridDim.x * 256)
        atomicAdd(&lh[dst[e] >> BSH], 1);
    __syncthreads();
    for (int i = threadIdx.x; i < K; i += 256)
        if (lh[i]) atomicAdd(&bhist[i], lh[i]);
}

__global__ __launch_bounds__(512) void bscan_kernel(
        const int* __restrict__ bhist, int* __restrict__ bbase, int* __restrict__ bcur,
        int* __restrict__ rp, int K, int E, int N) {
    __shared__ int sm[512];
    int t = threadIdx.x;
    int v = (t < K) ? bhist[t] : 0;
    sm[t] = v;
    __syncthreads();
    for (int off = 1; off < 512; off <<= 1) {
        int add = (t >= off) ? sm[t - off] : 0;
        __syncthreads();
        sm[t] += add;
        __syncthreads();
    }
    if (t < K) { bbase[t] = sm[t] - v; bcur[t * BPAD] = sm[t] - v; }
    if (t == 0) { bbase[K] = E; rp[N] = E; }
}

// Block-local multi-split partition (R6: ~1-2 writebacks per pairs-line,
// independent of block->XCD placement).
__global__ __launch_bounds__(256) void partition_kernel(
        const int* __restrict__ src, const int* __restrict__ dst,
        int* __restrict__ bcur, int* __restrict__ pairs, int E) {
    __shared__ int   lcnt[512];
    __shared__ int   lstart[512];
    __shared__ int   ldelta[512];
    __shared__ int   sm[256];
    __shared__ int   staged[CH];
    __shared__ short binof[CH];
    int t = threadIdx.x;
    int base = blockIdx.x * CH;
    int n = min(CH, E - base);

    lcnt[t] = 0; lcnt[t + 256] = 0;
    __syncthreads();

    int pk[CHT]; int bn[CHT];
    #pragma unroll
    for (int j = 0; j < CHT; ++j) {
        int i = t + j * 256;
        bn[j] = -1;
        if (i < n) {
            int d = dst[base + i];
            int s = src[base + i];
            bn[j] = d >> BSH;
            pk[j] = ((d & ((1 << BSH) - 1)) << 17) | s;
            atomicAdd(&lcnt[bn[j]], 1);
        }
    }
    __syncthreads();

    int c0 = lcnt[2 * t], c1 = lcnt[2 * t + 1];
    int s2 = c0 + c1;
    sm[t] = s2;
    __syncthreads();
    for (int off = 1; off < 256; off <<= 1) {
        int add = (t >= off) ? sm[t - off] : 0;
        __syncthreads();
        sm[t] += add;
        __syncthreads();
    }
    int ex = sm[t] - s2;
    lstart[2 * t] = ex;     lstart[2 * t + 1] = ex + c0;
    lcnt[2 * t]   = ex;     lcnt[2 * t + 1]   = ex + c0;
    __syncthreads();

    #pragma unroll
    for (int j = 0; j < CHT; ++j) {
        if (bn[j] >= 0) {
            int pos = atomicAdd(&lcnt[bn[j]], 1);
            staged[pos] = pk[j];
            binof[pos] = (short)bn[j];
        }
    }
    __syncthreads();

    #pragma unroll
    for (int k = 0; k < 2; ++k) {
        int b = 2 * t + k;
        int cnt = lcnt[b] - lstart[b];
        if (cnt > 0) {
            int g = atomicAdd(&bcur[b * BPAD], cnt);
            ldelta[b] = g - lstart[b];
        }
    }
    __syncthreads();

    for (int i = t; i < n; i += 256)
        pairs[ldelta[binof[i]] + i] = staged[i];
}

__global__ __launch_bounds__(256) void build_kernel(
        const int* __restrict__ pairs, const int* __restrict__ bbase,
        int* __restrict__ rp, float* __restrict__ dis, int* __restrict__ col, int N) {
    __shared__ int lcnt[1 << BSH];
    __shared__ int lsum[1 << BSH];
    __shared__ int lbase[1 << BSH];
    int b = blockIdx.x;
    int t = threadIdx.x;
    int nbase = b << BSH;
    int nn = min(1 << BSH, N - nbase);
    int beg = bbase[b], end = bbase[b + 1];
    if (t < 128) lcnt[t] = 0;
    __syncthreads();
    for (int e = beg + t; e < end; e += 256)
        atomicAdd(&lcnt[pairs[e] >> 17], 1);
    __syncthreads();
    if (t < 128) lsum[t] = lcnt[t];
    __syncthreads();
    for (int off = 1; off < 128; off <<= 1) {
        int add = (t < 128 && t >= off) ? lsum[t - off] : 0;
        __syncthreads();
        if (t < 128) lsum[t] += add;
        __syncthreads();
    }
    if (t < 128) {
        int excl = beg + lsum[t] - lcnt[t];
        lbase[t] = excl;
        if (t < nn) {
            rp[nbase + t] = excl;
            dis[nbase + t] = rsqrtf((float)(lcnt[t] + 1));  // deg incl. self-loop
        }
    }
    __syncthreads();
    if (t < 128) lcnt[t] = lbase[t];
    __syncthreads();
    for (int e = beg + t; e < end; e += 256) {
        int p = pairs[e];
        int pos = atomicAdd(&lcnt[p >> 17], 1);
        col[pos] = p & 0x1FFFF;
    }
}

// ---------------- precision prep ----------------

// fp32 -> bf16 row-major (x)
__global__ void cvt_kernel(const float4* __restrict__ in, uint2* __restrict__ outp, int n4) {
    int i = blockIdx.x * blockDim.x + threadIdx.x;
    if (i < n4) {
        float4 v = in[i];
        uint2 o;
        o.x = bfr(v.x) | (bfr(v.y) << 16);
        o.y = bfr(v.z) | (bfr(v.w) << 16);
        outp[i] = o;
    }
}

// W[k][n] fp32 -> WT[n][k] bf16 (transposed so B-fragments are contiguous in LDS)
__global__ void wt_kernel(const float* __restrict__ W, unsigned short* __restrict__ WT) {
    int k = blockIdx.x;
    int n = threadIdx.x;
    WT[n * FD + k] = (unsigned short)bfr(W[k * FD + n]);
}

// ---------------- MFMA bf16 GEMM: C = bf16( dis[row] * (A @ W) ) ----------------
// A: [M x 128] bf16 row-major.  WT: [128 x 128] bf16, WT[n][k].
// Block: 128 rows, full K=128 and N=128 in LDS. 4 waves, 32 rows each.
// Mappings (guide-verified): A[m=lane&15][k=quad*8+j], B[k=quad*8+j][n=lane&15],
// C/D row=quad*4+reg, col=lane&15.

#define APAD 8
#define ASTR (FD + APAD)

__global__ __launch_bounds__(256) void gemm_mfma(
        const unsigned short* __restrict__ A, const unsigned short* __restrict__ WT,
        const float* __restrict__ dis, unsigned short* __restrict__ C, int M) {
    __shared__ unsigned short As[128 * ASTR];
    __shared__ unsigned short Bs[128 * ASTR];
    int tid = threadIdx.x;
    int lane = tid & 63;
    int wave = tid >> 6;
    int quad = lane >> 4;
    int l16 = lane & 15;
    int rowBase = blockIdx.x * 128;

    // stage A-tile (zero-padded past M) and WT
    #pragma unroll
    for (int p = 0; p < 8; ++p) {
        int r = p * 16 + (tid >> 4);
        int cq = (tid & 15) * 8;
        uint4 v = make_uint4(0u, 0u, 0u, 0u);
        int gr = rowBase + r;
        if (gr < M) v = *(const uint4*)&A[(size_t)gr * FD + cq];
        *(uint4*)&As[r * ASTR + cq] = v;
        *(uint4*)&Bs[r * ASTR + cq] = *(const uint4*)&WT[(size_t)r * FD + cq];
    }
    __syncthreads();

    int m0 = wave * 32;
    f32x4 acc[2][8] = {};
    #pragma unroll
    for (int kt = 0; kt < 4; ++kt) {
        int ko = kt * 32 + quad * 8;
        bf16x8 a0 = *(bf16x8*)&As[(m0 + l16) * ASTR + ko];
        bf16x8 a1 = *(bf16x8*)&As[(m0 + 16 + l16) * ASTR + ko];
        #pragma unroll
        for (int n = 0; n < 8; ++n) {
            bf16x8 b = *(bf16x8*)&Bs[(n * 16 + l16) * ASTR + ko];
            acc[0][n] = __builtin_amdgcn_mfma_f32_16x16x32_bf16(a0, b, acc[0][n], 0, 0, 0);
            acc[1][n] = __builtin_amdgcn_mfma_f32_16x16x32_bf16(a1, b, acc[1][n], 0, 0, 0);
        }
    }

    #pragma unroll
    for (int ms = 0; ms < 2; ++ms) {
        #pragma unroll
        for (int r = 0; r < 4; ++r) {
            int grow = rowBase + m0 + ms * 16 + quad * 4 + r;
            if (grow < M) {
                float dv = dis[grow];
                #pragma unroll
                for (int n = 0; n < 8; ++n) {
                    C[(size_t)grow * FD + n * 16 + l16] =
                        (unsigned short)bfr(dv * acc[ms][n][r]);
                }
            }
        }
    }
}

// ---------------- CSR aggregation + bias + ReLU ----------------
// h' rows pre-scaled by dis, stored bf16 (2 per uint).
// out[v] = relu( dis[v] * ( h'[v] + sum_u h'[u] ) + b )
// obf=1: write packed bf16 (z1, feeds gemm2); obf=0: write fp32 (final out).

__global__ __launch_bounds__(256) void agg_kernel(
        const unsigned* __restrict__ h, const float* __restrict__ dis,
        const int* __restrict__ rp, const int* __restrict__ col,
        const float2* __restrict__ bias, void* __restrict__ out, int N, int obf) {
    int v = blockIdx.x * 4 + threadIdx.y;          // blockDim = (64, 4): wave per node
    v = __builtin_amdgcn_readfirstlane(v);         // wave-uniform -> scalar rp/col loads
    if (v >= N) return;
    int t = threadIdx.x;
    float dv = dis[v];
    size_t vb = (size_t)v * 64 + t;
    unsigned hp = h[vb];                           // self term h'[v]
    float2 acc;
    acc.x = uplo(hp); acc.y = uphi(hp);
    int e = rp[v];
    int end = rp[v + 1];
    for (; e + 8 <= end; e += 8) {
        int u0 = col[e],     u1 = col[e + 1], u2 = col[e + 2], u3 = col[e + 3];
        int u4 = col[e + 4], u5 = col[e + 5], u6 = col[e + 6], u7 = col[e + 7];
        unsigned p0 = h[(size_t)u0 * 64 + t];
        unsigned p1 = h[(size_t)u1 * 64 + t];
        unsigned p2 = h[(size_t)u2 * 64 + t];
        unsigned p3 = h[(size_t)u3 * 64 + t];
        unsigned p4 = h[(size_t)u4 * 64 + t];
        unsigned p5 = h[(size_t)u5 * 64 + t];
        unsigned p6 = h[(size_t)u6 * 64 + t];
        unsigned p7 = h[(size_t)u7 * 64 + t];
        acc.x += uplo(p0); acc.y += uphi(p0);
        acc.x += uplo(p1); acc.y += uphi(p1);
        acc.x += uplo(p2); acc.y += uphi(p2);
        acc.x += uplo(p3); acc.y += uphi(p3);
        acc.x += uplo(p4); acc.y += uphi(p4);
        acc.x += uplo(p5); acc.y += uphi(p5);
        acc.x += uplo(p6); acc.y += uphi(p6);
        acc.x += uplo(p7); acc.y += uphi(p7);
    }
    for (; e < end; ++e) {
        unsigned p = h[(size_t)col[e] * 64 + t];
        acc.x += uplo(p); acc.y += uphi(p);
    }
    float2 bb = bias[t];
    float2 r;
    r.x = fmaxf(fmaf(dv, acc.x, bb.x), 0.0f);
    r.y = fmaxf(fmaf(dv, acc.y, bb.y), 0.0f);
    if (obf) {
        ((unsigned*)out)[vb] = bfr(r.x) | (bfr(r.y) << 16);
    } else {
        ((float2*)out)[vb] = r;
    }
}

// ---------------- launch ----------------

extern "C" void kernel_launch(void* const* d_in, const int* in_sizes, int n_in,
                              void* d_out, int out_size, void* d_ws, size_t ws_size,
                              hipStream_t stream) {
    const float* x  = (const float*)d_in[0];
    const int*   ei = (const int*)d_in[1];   // [2, E] int32
    const float* W1 = (const float*)d_in[2];
    const float* b1 = (const float*)d_in[3];
    const float* W2 = (const float*)d_in[4];
    const float* b2 = (const float*)d_in[5];

    int N = in_sizes[0] / FD;
    int E = in_sizes[1] / 2;
    const int* src = ei;
    const int* dst = ei + E;
    int K = (N + (1 << BSH) - 1) >> BSH;     // buckets (<= 512 assumed)

    char* base = (char*)d_ws;
    size_t off = 0;
    auto align256 = [](size_t v) { return (v + 255) & ~(size_t)255; };
    int*            rp    = (int*)(base + off);            off += align256((size_t)(N + 1) * 4);
    float*          dis   = (float*)(base + off);          off += align256((size_t)N * 4);
    int*            bhist = (int*)(base + off);            off += align256(512 * 4);
    int*            bbase = (int*)(base + off);            off += align256(513 * 4);
    int*            bcur  = (int*)(base + off);            off += align256((size_t)K * BPAD * 4);
    unsigned short* w1t   = (unsigned short*)(base + off); off += align256((size_t)FD * FD * 2);
    unsigned short* w2t   = (unsigned short*)(base + off); off += align256((size_t)FD * FD * 2);
    int*            col   = (int*)(base + off);            off += align256((size_t)E * 4);
    unsigned short* hbuf  = (unsigned short*)(base + off); off += align256((size_t)N * FD * 2);
    unsigned short* xz    = (unsigned short*)(base + off); off += align256((size_t)N * FD * 2);
    int*            pairs = (int*)(base + off);            off += align256((size_t)E * 4);
    (void)ws_size; (void)n_in; (void)out_size;
    // xz: holds bf16(x) until gemm1 reads it, then reused as bf16 z1 by agg1.

    int PB = (E + CH - 1) / CH;
    int n4 = N * FD / 4;

    hipMemsetAsync(bhist, 0, 512 * 4, stream);
    hist_kernel     <<<1024, 256, 0, stream>>>(dst, bhist, E, K);
    bscan_kernel    <<<1, 512, 0, stream>>>(bhist, bbase, bcur, rp, K, E, N);
    partition_kernel<<<PB, 256, 0, stream>>>(src, dst, bcur, pairs, E);
    build_kernel    <<<K, 256, 0, stream>>>(pairs, bbase, rp, dis, col, N);

    cvt_kernel<<<(n4 + 255) / 256, 256, 0, stream>>>((const float4*)x, (uint2*)xz, n4);
    wt_kernel <<<FD, FD, 0, stream>>>(W1, w1t);
    wt_kernel <<<FD, FD, 0, stream>>>(W2, w2t);

    dim3 aggBlk(64, 4);
    int aggGrid = (N + 3) / 4;
    int gemmGrid = (N + 127) / 128;

    gemm_mfma<<<gemmGrid, 256, 0, stream>>>(xz, w1t, dis, hbuf, N);
    agg_kernel<<<aggGrid, aggBlk, 0, stream>>>((const unsigned*)hbuf, dis, rp, col,
                                               (const float2*)b1, xz, N, 1);
    gemm_mfma<<<gemmGrid, 256, 0, stream>>>(xz, w2t, dis, hbuf, N);
    agg_kernel<<<aggGrid, aggBlk, 0, stream>>>((const unsigned*)hbuf, dis, rp, col,
                                               (const float2*)b2, d_out, N, 0);
}